// Round 18
// baseline (120.793 us; speedup 1.0000x reference)
//
#include <hip/hip_runtime.h>

static constexpr int NN   = 50000;    // nodes per batch
static constexpr int NBAT = 4;
static constexpr int NE   = 1600000;  // unique edges
static constexpr int NC   = 1000;
static constexpr int FN   = 64;
static constexpr int FCOL = 32;
static constexpr int HD   = 16;

// two-level partition geometry
static constexpr int NP     = 20;      // level-1 partitions (2500 nodes each)
static constexpr int PNODES = 2500;
static constexpr int PCAP   = 88000;   // mean 80000 (+29 sigma)
static constexpr int NSUB   = 1000;    // level-2 sub-ranges (50 nodes each)
static constexpr int SNODES = 50;
static constexpr int SCAP   = 2048;    // mean 1600 (+11 sigma)
static constexpr int SPP    = 50;      // subs per partition
static constexpr int SLICES = 44;      // part2 blocks per partition (44*2048 >= PCAP)
static constexpr int CHUNK1 = 2048;    // edges per part1 block (782 blocks, ~3/CU)
static constexpr int CHUNK2 = 2048;    // entries per part2 block

static constexpr int P1B  = (NE + CHUNK1 - 1) / CHUNK1; // 782
static constexpr int MLPB = (NN + 127) / 128;           // 391 per batch
static constexpr int COLB = 16;                         // 4 chunks x 4 batches

// ---------- block reduction (256 threads, wave64) ----------
__device__ inline float block_reduce_256(float v) {
    __shared__ float s[4];
    int lane = threadIdx.x & 63, wid = threadIdx.x >> 6;
    #pragma unroll
    for (int o = 32; o > 0; o >>= 1) v += __shfl_down(v, o);
    if (lane == 0) s[wid] = v;
    __syncthreads();
    if (threadIdx.x == 0) {
        float t = 0.f;
        #pragma unroll
        for (int i = 0; i < 4; i++) t += s[i];
        return t;
    }
    return 0.f;
}

__device__ inline float dot4(float4 a, float4 w) {
    return (a.x * w.x + a.y * w.y) + (a.z * w.z + a.w * w.w);
}

// quad reduce-scatter: p[16] partials -> lane q holds t[4q..4q+4). Static indices.
__device__ inline float4 quad_reduce_scatter(const float (&p)[16], int q) {
    constexpr int KA[8] = {0,1,2,3,8,9,10,11};
    constexpr int KB[8] = {4,5,6,7,12,13,14,15};
    bool hi1 = (q & 1);
    float m[8];
    #pragma unroll
    for (int i = 0; i < 8; i++) {
        float send = hi1 ? p[KA[i]] : p[KB[i]];
        float recv = __shfl_xor(send, 1);
        m[i] = (hi1 ? p[KB[i]] : p[KA[i]]) + recv;
    }
    bool hi2 = (q & 2);
    float s0 = hi2 ? m[0] : m[4];
    float s1 = hi2 ? m[1] : m[5];
    float s2 = hi2 ? m[2] : m[6];
    float s3 = hi2 ? m[3] : m[7];
    float v0 = __shfl_xor(s0, 2);
    float v1 = __shfl_xor(s1, 2);
    float v2 = __shfl_xor(s2, 2);
    float v3 = __shfl_xor(s3, 2);
    return make_float4((hi2 ? m[4] : m[0]) + v0, (hi2 ? m[5] : m[1]) + v1,
                       (hi2 ? m[6] : m[2]) + v2, (hi2 ? m[7] : m[3]) + v3);
}

__device__ inline float mlp_tail(float4 t, int q, bool valid, const float* sw2,
                                 float4 bv, float4 b2v, float4 nfv) {
    float h0 = fmaxf(t.x + bv.x, 0.f);
    float h1 = fmaxf(t.y + bv.y, 0.f);
    float h2 = fmaxf(t.z + bv.z, 0.f);
    float h3 = fmaxf(t.w + bv.w, 0.f);
    float pk[16];
    const float* r0p = &sw2[(q * 4 + 0) * 20];
    const float* r1p = &sw2[(q * 4 + 1) * 20];
    const float* r2p = &sw2[(q * 4 + 2) * 20];
    const float* r3p = &sw2[(q * 4 + 3) * 20];
    #pragma unroll
    for (int k4 = 0; k4 < 4; k4++) {
        float4 w0 = *(const float4*)&r0p[k4 * 4];
        float4 w1 = *(const float4*)&r1p[k4 * 4];
        float4 w2 = *(const float4*)&r2p[k4 * 4];
        float4 w3 = *(const float4*)&r3p[k4 * 4];
        pk[k4*4+0] = h0 * w0.x + h1 * w1.x + h2 * w2.x + h3 * w3.x;
        pk[k4*4+1] = h0 * w0.y + h1 * w1.y + h2 * w2.y + h3 * w3.y;
        pk[k4*4+2] = h0 * w0.z + h1 * w1.z + h2 * w2.z + h3 * w3.z;
        pk[k4*4+3] = h0 * w0.w + h1 * w1.w + h2 * w2.w + h3 * w3.w;
    }
    float4 f = quad_reduce_scatter(pk, q);
    float sv = fmaxf(f.x + b2v.x, 0.f) * nfv.x
             + fmaxf(f.y + b2v.y, 0.f) * nfv.y
             + fmaxf(f.z + b2v.z, 0.f) * nfv.z
             + fmaxf(f.w + b2v.w, 0.f) * nfv.w;
    return valid ? sv : 0.f;
}

// ---------- part1: partition edges into NP dst-ranges (standalone) ----------
__global__ void __launch_bounds__(256) k_part1(
        const int* __restrict__ src, const int* __restrict__ dst,
        int* __restrict__ gcur, unsigned* __restrict__ buf1) {
    __shared__ int ph[NP], pg[NP], pl[NP];
    int tid = threadIdx.x;
    if (tid < NP) ph[tid] = 0;
    __syncthreads();
    int e0 = blockIdx.x * CHUNK1;
    unsigned ent[8]; int bin[8];
    #pragma unroll
    for (int k = 0; k < 8; k++) {
        int e = e0 + k * 256 + tid;
        if (e < NE) {
            unsigned d = (unsigned)dst[e], s = (unsigned)src[e];
            ent[k] = (d << 16) | s;
            bin[k] = (int)(d / (unsigned)PNODES);
            atomicAdd(&ph[bin[k]], 1);
        } else bin[k] = -1;
    }
    __syncthreads();
    if (tid < NP) { pg[tid] = atomicAdd(&gcur[tid], ph[tid]); pl[tid] = 0; }
    __syncthreads();
    #pragma unroll
    for (int k = 0; k < 8; k++) {
        if (bin[k] >= 0) {
            int p = pg[bin[k]] + atomicAdd(&pl[bin[k]], 1);
            if (p < PCAP) buf1[(size_t)bin[k] * PCAP + p] = ent[k];
        }
    }
}

// ---------- xmlp+col: all-batch x@W1 (+MLP reduce) | col ----------
__global__ void __launch_bounds__(256) k_xmlpcol(
        const float* __restrict__ x, const float* __restrict__ col,
        const float* __restrict__ W1, const float* __restrict__ b1,
        const float* __restrict__ W2, const float* __restrict__ b2,
        const float* __restrict__ nfcW,
        const float* __restrict__ cW1, const float* __restrict__ cb1,
        const float* __restrict__ cW2,
        float* __restrict__ y1, double* __restrict__ sums) {
    __shared__ float swt[HD * FN];                    // MLP: [j][k]
    __shared__ float sw2[HD * 20];                    // MLP: padded W2 rows
    __shared__ float sb1[HD], sb2[HD], snf[HD];
    __shared__ float cw1s[FCOL * HD], csb1[HD], csw2[HD];   // col

    int tid = threadIdx.x;
    int idx = blockIdx.x;

    if (idx < NBAT * MLPB) {
        // ================= x@W1 / MLP =================
        int b = idx / MLPB, nb = idx - b * MLPB;
        int q = tid & 3;
        int n0 = nb * 128 + (tid >> 2) * 2;
        bool v0 = (n0 < NN), v1 = (n0 + 1 < NN);
        const float* xb = x + (size_t)b * NN * FN;

        float4 a0, a1, a2, a3, c0, c1, c2, c3;
        a0 = a1 = a2 = a3 = c0 = c1 = c2 = c3 = make_float4(0.f, 0.f, 0.f, 0.f);
        if (v0) {
            const float4* p = (const float4*)(xb + (size_t)n0 * FN + q * 16);
            a0 = p[0]; a1 = p[1]; a2 = p[2]; a3 = p[3];
        }
        if (v1) {
            const float4* p = (const float4*)(xb + (size_t)(n0 + 1) * FN + q * 16);
            c0 = p[0]; c1 = p[1]; c2 = p[2]; c3 = p[3];
        }

        #pragma unroll
        for (int i = tid; i < HD * FN; i += 256) {
            int j = i >> 6, k = i & 63;
            swt[i] = W1[k * HD + j];
        }
        if (tid < HD * HD) sw2[(tid >> 4) * 20 + (tid & 15)] = W2[tid];
        if (tid < HD) { sb1[tid] = b1[tid]; sb2[tid] = b2[tid]; snf[tid] = nfcW[tid]; }
        __syncthreads();

        float p0[16], p1[16];
        #pragma unroll
        for (int j = 0; j < HD; j++) {
            const float4* w = (const float4*)&swt[j * FN + q * 16];
            float4 w0 = w[0], w1 = w[1], w2 = w[2], w3 = w[3];
            p0[j] = (dot4(a0, w0) + dot4(a1, w1)) + (dot4(a2, w2) + dot4(a3, w3));
            p1[j] = (dot4(c0, w0) + dot4(c1, w1)) + (dot4(c2, w2) + dot4(c3, w3));
        }
        float4 r0 = quad_reduce_scatter(p0, q);
        float4 r1 = quad_reduce_scatter(p1, q);

        if (b == 0) {
            if (v0) *(float4*)&y1[(size_t)n0 * HD + q * 4] = r0;          // unscaled
            if (v1) *(float4*)&y1[(size_t)(n0 + 1) * HD + q * 4] = r1;    // (hist scales)
        } else {
            float4 bv  = *(const float4*)&sb1[q * 4];
            float4 b2v = *(const float4*)&sb2[q * 4];
            float4 nfv = *(const float4*)&snf[q * 4];
            float sv = mlp_tail(r0, q, v0, sw2, bv, b2v, nfv)
                     + mlp_tail(r1, q, v1, sw2, bv, b2v, nfv);
            float bs = block_reduce_256(sv);
            if (tid == 0) atomicAdd(&sums[b], (double)bs);
        }
        return;
    }

    // ================= col =================
    {
        int t = idx - NBAT * MLPB;
        int b = t & 3, chunk = t >> 2;
        for (int i = tid; i < FCOL * HD; i += 256) cw1s[i] = cW1[i];
        if (tid < HD) { csb1[tid] = cb1[tid]; csw2[tid] = cW2[tid]; }
        __syncthreads();
        int c = chunk * 256 + tid;
        float sv = 0.f;
        if (c < NC) {
            const float4* cf = (const float4*)(col + ((size_t)b * NC + c) * FCOL);
            float h[HD];
            #pragma unroll
            for (int j = 0; j < HD; j++) h[j] = csb1[j];
            #pragma unroll
            for (int k4 = 0; k4 < FCOL / 4; k4++) {
                float4 f = cf[k4];
                #pragma unroll
                for (int j = 0; j < HD; j++) {
                    h[j] += f.x * cw1s[(4 * k4 + 0) * HD + j];
                    h[j] += f.y * cw1s[(4 * k4 + 1) * HD + j];
                    h[j] += f.z * cw1s[(4 * k4 + 2) * HD + j];
                    h[j] += f.w * cw1s[(4 * k4 + 3) * HD + j];
                }
            }
            #pragma unroll
            for (int j = 0; j < HD; j++) sv += fmaxf(h[j], 0.f) * csw2[j];
        }
        float bs = block_reduce_256(sv);
        if (tid == 0) atomicAdd(&sums[4 + b], (double)bs);
    }
}

// ---------- pass 2: partition each level-1 bucket into SPP sub-ranges ----------
__global__ void __launch_bounds__(256) k_part2(
        const int* __restrict__ gcur, const unsigned* __restrict__ buf1,
        int* __restrict__ cur2, unsigned* __restrict__ buf2) {
    __shared__ int hist[SPP], gbase[SPP], lcur[SPP];
    int part = blockIdx.x / SLICES;
    int slice = blockIdx.x % SLICES;
    int count = min(gcur[part], PCAP);
    int base = slice * CHUNK2;
    if (base >= count) return;
    const unsigned* in = buf1 + (size_t)part * PCAP;
    int sub0 = part * SPP;
    int tid = threadIdx.x;
    if (tid < SPP) hist[tid] = 0;
    __syncthreads();
    unsigned ent[8]; int bin[8];
    #pragma unroll
    for (int k = 0; k < 8; k++) {
        int i = base + k * 256 + tid;
        if (i < count) {
            unsigned e = in[i];
            ent[k] = e;
            bin[k] = (int)((e >> 16) / (unsigned)SNODES) - sub0;
            atomicAdd(&hist[bin[k]], 1);
        } else bin[k] = -1;
    }
    __syncthreads();
    if (tid < SPP) { gbase[tid] = atomicAdd(&cur2[sub0 + tid], hist[tid]); lcur[tid] = 0; }
    __syncthreads();
    #pragma unroll
    for (int k = 0; k < 8; k++) {
        if (bin[k] >= 0) {
            int p = gbase[bin[k]] + atomicAdd(&lcur[bin[k]], 1);
            if (p < SCAP) buf2[(size_t)(sub0 + bin[k]) * SCAP + p] = ent[k];
        }
    }
}

// ---------- per-sub-range histogram -> cnt + dinv; also scales y1 -> z1 in place ----------
__global__ void __launch_bounds__(256) k_hist(
        const int* __restrict__ cur2, const unsigned* __restrict__ buf2,
        int* __restrict__ cnt, float* __restrict__ dinv, float* __restrict__ z1) {
    __shared__ int hist[SNODES];
    int tid = threadIdx.x, sub = blockIdx.x, vbase = sub * SNODES;
    if (tid < SNODES) hist[tid] = 0;
    __syncthreads();
    int count = min(cur2[sub], SCAP);
    const unsigned* in = buf2 + (size_t)sub * SCAP;
    for (int i = tid; i < count; i += 256)
        atomicAdd(&hist[(int)(in[i] >> 16) - vbase], 1);
    __syncthreads();
    if (tid < SNODES) {
        int c = hist[tid];
        cnt[vbase + tid] = c;
        dinv[vbase + tid] = rsqrtf((float)(4 * c + 1));
    }
    __syncthreads();
    if (tid < SNODES * 4) {
        int vl = tid >> 2, f4 = tid & 3;
        float dv = rsqrtf((float)(4 * hist[vl] + 1));
        float4* p = (float4*)&z1[(size_t)(vbase + vl) * HD + f4 * 4];
        float4 v = *p;
        *p = make_float4(dv * v.x, dv * v.y, dv * v.z, dv * v.w);
    }
}

// ---------- in-LDS counting sort using precomputed cnt + parallel scan ----------
__device__ inline void sort_sublist(int sub, const int* __restrict__ cur2,
                                    const int* __restrict__ cnt,
                                    const unsigned* __restrict__ buf2,
                                    unsigned* sorted, int* rp, int* cur, int* s) {
    int tid = threadIdx.x, vbase = sub * SNODES;
    int own = (tid < SNODES) ? cnt[vbase + tid] : 0;
    if (tid < 64) s[tid] = own;
    __syncthreads();
    #pragma unroll
    for (int off = 1; off < 64; off <<= 1) {
        int v = (tid < 64 && tid >= off) ? s[tid - off] : 0;
        __syncthreads();
        if (tid < 64) s[tid] += v;
        __syncthreads();
    }
    if (tid < SNODES) {
        int excl = s[tid] - own;
        rp[tid] = excl;
        cur[tid] = excl;
    }
    if (tid == SNODES - 1) rp[SNODES] = s[tid];
    __syncthreads();
    int count = min(cur2[sub], SCAP);
    const unsigned* in = buf2 + (size_t)sub * SCAP;
    for (int i = tid; i < count; i += 256) {
        unsigned e = in[i];
        int p = atomicAdd(&cur[(int)(e >> 16) - vbase], 1);
        sorted[p] = e;
    }
    __syncthreads();
}

__device__ inline void load_sorted(int sub, const int* __restrict__ cur2,
                                   const int* __restrict__ cnt,
                                   const unsigned* __restrict__ buf2,
                                   unsigned* sorted, int* rp, int* s) {
    int tid = threadIdx.x, vbase = sub * SNODES;
    int own = (tid < SNODES) ? cnt[vbase + tid] : 0;
    if (tid < 64) s[tid] = own;
    __syncthreads();
    #pragma unroll
    for (int off = 1; off < 64; off <<= 1) {
        int v = (tid < 64 && tid >= off) ? s[tid - off] : 0;
        __syncthreads();
        if (tid < 64) s[tid] += v;
        __syncthreads();
    }
    if (tid < SNODES) rp[tid] = s[tid] - own;
    if (tid == SNODES - 1) rp[SNODES] = s[tid];
    __syncthreads();
    int count = min(cur2[sub], SCAP);
    const unsigned* in = buf2 + (size_t)sub * SCAP;
    for (int i = tid; i < count; i += 256) sorted[i] = in[i];
    __syncthreads();
}

// ---------- per-node register gather over a sorted run (8 loads in flight) ----------
__device__ inline float gather_run(const unsigned* sorted, int s0, int s1,
                                   const float* __restrict__ z, int j) {
    float acc = 0.f;
    int i = s0;
    for (; i + 8 <= s1; i += 8) {
        unsigned e0 = sorted[i],   e1 = sorted[i+1], e2 = sorted[i+2], e3 = sorted[i+3];
        unsigned e4 = sorted[i+4], e5 = sorted[i+5], e6 = sorted[i+6], e7 = sorted[i+7];
        float v0 = z[(e0 & 0xffffu) * HD + j];
        float v1 = z[(e1 & 0xffffu) * HD + j];
        float v2 = z[(e2 & 0xffffu) * HD + j];
        float v3 = z[(e3 & 0xffffu) * HD + j];
        float v4 = z[(e4 & 0xffffu) * HD + j];
        float v5 = z[(e5 & 0xffffu) * HD + j];
        float v6 = z[(e6 & 0xffffu) * HD + j];
        float v7 = z[(e7 & 0xffffu) * HD + j];
        acc += ((v0 + v1) + (v2 + v3)) + ((v4 + v5) + (v6 + v7));
    }
    for (; i + 4 <= s1; i += 4) {
        unsigned a = sorted[i], b = sorted[i+1], c = sorted[i+2], d = sorted[i+3];
        float va = z[(a & 0xffffu) * HD + j];
        float vb = z[(b & 0xffffu) * HD + j];
        float vc = z[(c & 0xffffu) * HD + j];
        float vd = z[(d & 0xffffu) * HD + j];
        acc += (va + vb) + (vc + vd);
    }
    for (; i < s1; i++) acc += z[(sorted[i] & 0xffffu) * HD + j];
    return acc;
}

// ---------- conv1: sort + gather z1, finalize, z2 = dinv*(relu(.)@W2) ----------
__global__ void __launch_bounds__(256) k_conv1(
        const int* __restrict__ cur2, const int* __restrict__ cnt,
        unsigned* __restrict__ buf2,
        const float* __restrict__ dinv, const float* __restrict__ z1,
        const float* __restrict__ b1, const float* __restrict__ W2,
        float* __restrict__ z2) {
    __shared__ unsigned sorted[SCAP];
    __shared__ int rp[SNODES + 1], cur[SNODES], s[64];
    __shared__ float sW[HD * HD], sb[HD];
    int tid = threadIdx.x;
    if (tid < HD * HD) sW[tid] = W2[tid];
    if (tid < HD) sb[tid] = b1[tid];
    int sub = blockIdx.x, vbase = sub * SNODES;
    sort_sublist(sub, cur2, cnt, buf2, sorted, rp, cur, s);

    {   // write back sorted list for conv2 (block owns this region exclusively)
        int count = min(cur2[sub], SCAP);
        unsigned* outp = buf2 + (size_t)sub * SCAP;
        for (int i = tid; i < count; i += 256) outp[i] = sorted[i];
    }

    int j = tid & 15, g = tid >> 4;
    int sbase = (tid & 63) & 48;
    #pragma unroll
    for (int it = 0; it < (SNODES + 15) / 16; it++) {
        int lv = it * 16 + g;
        bool valid = (lv < SNODES);
        float h = 0.f, dv = 0.f;
        if (valid) {
            float acc = gather_run(sorted, rp[lv], rp[lv + 1], z1, j);
            int v = vbase + lv;
            dv = dinv[v];
            h = fmaxf(4.f * dv * acc + dv * z1[v * HD + j] + sb[j], 0.f);
        }
        float o = 0.f;
        #pragma unroll
        for (int k = 0; k < HD; k++) o += __shfl(h, sbase + k) * sW[k * HD + j];
        if (valid) z2[(vbase + lv) * HD + j] = dv * o;
    }
}

// ---------- conv2: load pre-sorted + gather z2, finalize, dot nfcW, reduce ----------
__global__ void __launch_bounds__(256) k_conv2(
        const int* __restrict__ cur2, const int* __restrict__ cnt,
        const unsigned* __restrict__ buf2,
        const float* __restrict__ dinv, const float* __restrict__ z2,
        const float* __restrict__ b2, const float* __restrict__ nfcW,
        double* __restrict__ sums) {
    __shared__ unsigned sorted[SCAP];
    __shared__ int rp[SNODES + 1], s[64];
    __shared__ float sb[HD], sw[HD];
    int tid = threadIdx.x;
    if (tid < HD) { sb[tid] = b2[tid]; sw[tid] = nfcW[tid]; }
    int sub = blockIdx.x, vbase = sub * SNODES;
    load_sorted(sub, cur2, cnt, buf2, sorted, rp, s);

    int j = tid & 15, g = tid >> 4;
    float part = 0.f;
    #pragma unroll
    for (int it = 0; it < (SNODES + 15) / 16; it++) {
        int lv = it * 16 + g;
        if (lv < SNODES) {
            float acc = gather_run(sorted, rp[lv], rp[lv + 1], z2, j);
            int v = vbase + lv;
            float dv = dinv[v];
            float h = fmaxf(4.f * dv * acc + dv * z2[v * HD + j] + sb[j], 0.f);
            part += h * sw[j];
        }
    }
    float bs = block_reduce_256(part);
    if (tid == 0) atomicAdd(&sums[0], (double)bs);
}

// ---------- final tiny head ----------
__global__ void k_final(const double* __restrict__ sums,
                        const float* __restrict__ nfcb, const float* __restrict__ cb2,
                        const float* __restrict__ fcW, const float* __restrict__ fcb,
                        const float* __restrict__ outW, const float* __restrict__ outb,
                        float* __restrict__ out) {
    int b = threadIdx.x;
    if (b < NBAT) {
        float na = (float)(sums[b] * (1.0 / NN)) + nfcb[0];
        float ca = (float)(sums[4 + b] * (1.0 / NC)) + cb2[0];
        float o = outb[0];
        #pragma unroll
        for (int j = 0; j < HD; j++) {
            float z = fmaxf(na * fcW[j] + ca * fcW[HD + j] + fcb[j], 0.f);
            o += z * outW[j];
        }
        out[b] = o;
    }
}

extern "C" void kernel_launch(void* const* d_in, const int* in_sizes, int n_in,
                              void* d_out, int out_size, void* d_ws, size_t ws_size,
                              hipStream_t stream) {
    const float* x    = (const float*)d_in[0];
    const float* col  = (const float*)d_in[1];
    const int*   ei   = (const int*)d_in[2];
    const float* W1   = (const float*)d_in[3];
    const float* b1   = (const float*)d_in[4];
    const float* W2   = (const float*)d_in[5];
    const float* b2   = (const float*)d_in[6];
    const float* nfcW = (const float*)d_in[7];
    const float* nfcb = (const float*)d_in[8];
    const float* cW1  = (const float*)d_in[9];
    const float* cb1  = (const float*)d_in[10];
    const float* cW2  = (const float*)d_in[11];
    const float* cb2  = (const float*)d_in[12];
    const float* fcW  = (const float*)d_in[13];
    const float* fcb  = (const float*)d_in[14];
    const float* outW = (const float*)d_in[15];
    const float* outb = (const float*)d_in[16];
    float* out = (float*)d_out;

    char* ws = (char*)d_ws;
    int*      gcur = (int*)     (ws + 0);          // 20 int
    int*      cur2 = (int*)     (ws + 128);        // 1000 int -> ends 4128
    double*   sums = (double*)  (ws + 4160);       // 8 doubles, own cache line -> ends 4224
    int*      cnt  = (int*)     (ws + 4224);       // 200000 B -> ends 204224
    float*    dinv = (float*)   (ws + 204224);     // 200000 B -> ends 404224
    unsigned* buf1 = (unsigned*)(ws + 404480);     // 7,040,000 B -> ends 7,444,480
    float*    z2   = (float*)   (ws + 404480);     // overlay on buf1 (dead after part2)
    float*    z1   = (float*)   (ws + 7444480);    // 3,200,000 B -> ends 10,644,480
    unsigned* buf2 = (unsigned*)(ws + 10644480);   // 8,192,000 B -> ends 18,836,480

    const int* src = ei;
    const int* dst = ei + NE;

    hipMemsetAsync(gcur, 0, 4224, stream);   // gcur + cur2 + sums in one dispatch

    k_part1 <<<P1B, 256, 0, stream>>>(src, dst, gcur, buf1);
    k_xmlpcol<<<NBAT * MLPB + COLB, 256, 0, stream>>>(x, col, W1, b1, W2, b2,
                                                      nfcW, cW1, cb1, cW2, z1, sums);
    k_part2<<<NP * SLICES, 256, 0, stream>>>(gcur, buf1, cur2, buf2);
    k_hist <<<NSUB, 256, 0, stream>>>(cur2, buf2, cnt, dinv, z1);
    k_conv1<<<NSUB, 256, 0, stream>>>(cur2, cnt, buf2, dinv, z1, b1, W2, z2);
    k_conv2<<<NSUB, 256, 0, stream>>>(cur2, cnt, buf2, dinv, z2, b2, nfcW, sums);
    k_final<<<1, 64, 0, stream>>>(sums, nfcb, cb2, fcW, fcb, outW, outb, out);
}

// Round 19
// 103.756 us; speedup vs baseline: 1.1642x; 1.1642x over previous
//
#include <hip/hip_runtime.h>

static constexpr int NN   = 50000;    // nodes per batch
static constexpr int NBAT = 4;
static constexpr int NE   = 1600000;  // unique edges
static constexpr int NC   = 1000;
static constexpr int FN   = 64;
static constexpr int FCOL = 32;
static constexpr int HD   = 16;

// two-level partition geometry
static constexpr int NP     = 20;      // level-1 partitions (2500 nodes each)
static constexpr int PNODES = 2500;
static constexpr int PCAP   = 88000;   // mean 80000 (+29 sigma)
static constexpr int NSUB   = 1000;    // level-2 sub-ranges (50 nodes each)
static constexpr int SNODES = 50;
static constexpr int SCAP   = 2048;    // mean 1600 (+11 sigma)
static constexpr int SPP    = 50;      // subs per partition
static constexpr int SLICES = 44;      // part2 blocks per partition (44*2048 >= PCAP)
static constexpr int CHUNK  = 4096;    // edges per part1 block-chunk
static constexpr int CHUNK2 = 2048;    // entries per part2 block

static constexpr int P1B  = (NE + CHUNK - 1) / CHUNK;   // 391
static constexpr int MLPB = (NN + 127) / 128;           // 391 per batch
static constexpr int COLB = 16;                         // 4 chunks x 4 batches
static constexpr int MEGAB = P1B + NBAT * MLPB + COLB;  // 1971

// ---------- block reduction (256 threads, wave64) ----------
__device__ inline float block_reduce_256(float v) {
    __shared__ float s[4];
    int lane = threadIdx.x & 63, wid = threadIdx.x >> 6;
    #pragma unroll
    for (int o = 32; o > 0; o >>= 1) v += __shfl_down(v, o);
    if (lane == 0) s[wid] = v;
    __syncthreads();
    if (threadIdx.x == 0) {
        float t = 0.f;
        #pragma unroll
        for (int i = 0; i < 4; i++) t += s[i];
        return t;
    }
    return 0.f;
}

__device__ inline float dot4(float4 a, float4 w) {
    return (a.x * w.x + a.y * w.y) + (a.z * w.z + a.w * w.w);
}

// quad reduce-scatter: p[16] partials -> lane q holds t[4q..4q+4). Static indices.
__device__ inline float4 quad_reduce_scatter(const float (&p)[16], int q) {
    constexpr int KA[8] = {0,1,2,3,8,9,10,11};
    constexpr int KB[8] = {4,5,6,7,12,13,14,15};
    bool hi1 = (q & 1);
    float m[8];
    #pragma unroll
    for (int i = 0; i < 8; i++) {
        float send = hi1 ? p[KA[i]] : p[KB[i]];
        float recv = __shfl_xor(send, 1);
        m[i] = (hi1 ? p[KB[i]] : p[KA[i]]) + recv;
    }
    bool hi2 = (q & 2);
    float s0 = hi2 ? m[0] : m[4];
    float s1 = hi2 ? m[1] : m[5];
    float s2 = hi2 ? m[2] : m[6];
    float s3 = hi2 ? m[3] : m[7];
    float v0 = __shfl_xor(s0, 2);
    float v1 = __shfl_xor(s1, 2);
    float v2 = __shfl_xor(s2, 2);
    float v3 = __shfl_xor(s3, 2);
    return make_float4((hi2 ? m[4] : m[0]) + v0, (hi2 ? m[5] : m[1]) + v1,
                       (hi2 ? m[6] : m[2]) + v2, (hi2 ? m[7] : m[3]) + v3);
}

__device__ inline float mlp_tail(float4 t, int q, bool valid, const float* sw2,
                                 float4 bv, float4 b2v, float4 nfv) {
    float h0 = fmaxf(t.x + bv.x, 0.f);
    float h1 = fmaxf(t.y + bv.y, 0.f);
    float h2 = fmaxf(t.z + bv.z, 0.f);
    float h3 = fmaxf(t.w + bv.w, 0.f);
    float pk[16];
    const float* r0p = &sw2[(q * 4 + 0) * 20];
    const float* r1p = &sw2[(q * 4 + 1) * 20];
    const float* r2p = &sw2[(q * 4 + 2) * 20];
    const float* r3p = &sw2[(q * 4 + 3) * 20];
    #pragma unroll
    for (int k4 = 0; k4 < 4; k4++) {
        float4 w0 = *(const float4*)&r0p[k4 * 4];
        float4 w1 = *(const float4*)&r1p[k4 * 4];
        float4 w2 = *(const float4*)&r2p[k4 * 4];
        float4 w3 = *(const float4*)&r3p[k4 * 4];
        pk[k4*4+0] = h0 * w0.x + h1 * w1.x + h2 * w2.x + h3 * w3.x;
        pk[k4*4+1] = h0 * w0.y + h1 * w1.y + h2 * w2.y + h3 * w3.y;
        pk[k4*4+2] = h0 * w0.z + h1 * w1.z + h2 * w2.z + h3 * w3.z;
        pk[k4*4+3] = h0 * w0.w + h1 * w1.w + h2 * w2.w + h3 * w3.w;
    }
    float4 f = quad_reduce_scatter(pk, q);
    float sv = fmaxf(f.x + b2v.x, 0.f) * nfv.x
             + fmaxf(f.y + b2v.y, 0.f) * nfv.y
             + fmaxf(f.z + b2v.z, 0.f) * nfv.z
             + fmaxf(f.w + b2v.w, 0.f) * nfv.w;
    return valid ? sv : 0.f;
}

// ---------- MEGA kernel: part1 | all-batch x@W1 (+MLP) | col, ROLE-STRIPED ----------
__global__ void __launch_bounds__(256) k_mega(
        const float* __restrict__ x, const int* __restrict__ src,
        const int* __restrict__ dst, const float* __restrict__ col,
        const float* __restrict__ W1, const float* __restrict__ b1,
        const float* __restrict__ W2, const float* __restrict__ b2,
        const float* __restrict__ nfcW,
        const float* __restrict__ cW1, const float* __restrict__ cb1,
        const float* __restrict__ cW2,
        int* __restrict__ gcur, unsigned* __restrict__ buf1,
        float* __restrict__ y1, double* __restrict__ sums) {
    __shared__ int ph[NP], pg[NP], pl[NP];            // part1
    __shared__ float swt[HD * FN];                    // MLP: [j][k]
    __shared__ float sw2[HD * 20];                    // MLP: padded W2 rows
    __shared__ float sb1[HD], sb2[HD], snf[HD];
    __shared__ float cw1s[FCOL * HD], csb1[HD], csw2[HD];   // col

    int tid = threadIdx.x;
    int idx = blockIdx.x;
    int i5 = idx / 5, r5 = idx - i5 * 5;
    bool isP1 = (r5 == 0) && (i5 < P1B);

    if (isP1) {
        // ================= part1 =================
        if (tid < NP) ph[tid] = 0;
        __syncthreads();
        int e0 = i5 * CHUNK;
        unsigned ent[16]; int bin[16];
        #pragma unroll
        for (int k = 0; k < 16; k++) {
            int e = e0 + k * 256 + tid;
            if (e < NE) {
                unsigned d = (unsigned)dst[e], s = (unsigned)src[e];
                ent[k] = (d << 16) | s;
                bin[k] = (int)(d / (unsigned)PNODES);
                atomicAdd(&ph[bin[k]], 1);
            } else bin[k] = -1;
        }
        __syncthreads();
        if (tid < NP) { pg[tid] = atomicAdd(&gcur[tid], ph[tid]); pl[tid] = 0; }
        __syncthreads();
        #pragma unroll
        for (int k = 0; k < 16; k++) {
            if (bin[k] >= 0) {
                int p = pg[bin[k]] + atomicAdd(&pl[bin[k]], 1);
                if (p < PCAP) buf1[(size_t)bin[k] * PCAP + p] = ent[k];
            }
        }
        return;
    }

    // non-part1 rank: subtract count of part1 slots at indices < idx
    int p1below = (i5 < P1B) ? (i5 + (r5 > 0 ? 1 : 0)) : P1B;
    int rank = idx - p1below;

    if (rank < NBAT * MLPB) {
        // ================= x@W1 / MLP =================
        int b = rank / MLPB, nb = rank - b * MLPB;
        int q = tid & 3;
        int n0 = nb * 128 + (tid >> 2) * 2;
        bool v0 = (n0 < NN), v1 = (n0 + 1 < NN);
        const float* xb = x + (size_t)b * NN * FN;

        float4 a0, a1, a2, a3, c0, c1, c2, c3;
        a0 = a1 = a2 = a3 = c0 = c1 = c2 = c3 = make_float4(0.f, 0.f, 0.f, 0.f);
        if (v0) {
            const float4* p = (const float4*)(xb + (size_t)n0 * FN + q * 16);
            a0 = p[0]; a1 = p[1]; a2 = p[2]; a3 = p[3];
        }
        if (v1) {
            const float4* p = (const float4*)(xb + (size_t)(n0 + 1) * FN + q * 16);
            c0 = p[0]; c1 = p[1]; c2 = p[2]; c3 = p[3];
        }

        #pragma unroll
        for (int i = tid; i < HD * FN; i += 256) {
            int j = i >> 6, k = i & 63;
            swt[i] = W1[k * HD + j];
        }
        if (tid < HD * HD) sw2[(tid >> 4) * 20 + (tid & 15)] = W2[tid];
        if (tid < HD) { sb1[tid] = b1[tid]; sb2[tid] = b2[tid]; snf[tid] = nfcW[tid]; }
        __syncthreads();

        float p0[16], p1[16];
        #pragma unroll
        for (int j = 0; j < HD; j++) {
            const float4* w = (const float4*)&swt[j * FN + q * 16];
            float4 w0 = w[0], w1 = w[1], w2 = w[2], w3 = w[3];
            p0[j] = (dot4(a0, w0) + dot4(a1, w1)) + (dot4(a2, w2) + dot4(a3, w3));
            p1[j] = (dot4(c0, w0) + dot4(c1, w1)) + (dot4(c2, w2) + dot4(c3, w3));
        }
        float4 r0 = quad_reduce_scatter(p0, q);
        float4 r1 = quad_reduce_scatter(p1, q);

        if (b == 0) {
            if (v0) *(float4*)&y1[(size_t)n0 * HD + q * 4] = r0;          // unscaled
            if (v1) *(float4*)&y1[(size_t)(n0 + 1) * HD + q * 4] = r1;    // (hist scales)
        } else {
            float4 bv  = *(const float4*)&sb1[q * 4];
            float4 b2v = *(const float4*)&sb2[q * 4];
            float4 nfv = *(const float4*)&snf[q * 4];
            float sv = mlp_tail(r0, q, v0, sw2, bv, b2v, nfv)
                     + mlp_tail(r1, q, v1, sw2, bv, b2v, nfv);
            float bs = block_reduce_256(sv);
            if (tid == 0) atomicAdd(&sums[b], (double)bs);
        }
        return;
    }

    // ================= col =================
    {
        int t = rank - NBAT * MLPB;
        int b = t & 3, chunk = t >> 2;
        for (int i = tid; i < FCOL * HD; i += 256) cw1s[i] = cW1[i];
        if (tid < HD) { csb1[tid] = cb1[tid]; csw2[tid] = cW2[tid]; }
        __syncthreads();
        int c = chunk * 256 + tid;
        float sv = 0.f;
        if (c < NC) {
            const float4* cf = (const float4*)(col + ((size_t)b * NC + c) * FCOL);
            float h[HD];
            #pragma unroll
            for (int j = 0; j < HD; j++) h[j] = csb1[j];
            #pragma unroll
            for (int k4 = 0; k4 < FCOL / 4; k4++) {
                float4 f = cf[k4];
                #pragma unroll
                for (int j = 0; j < HD; j++) {
                    h[j] += f.x * cw1s[(4 * k4 + 0) * HD + j];
                    h[j] += f.y * cw1s[(4 * k4 + 1) * HD + j];
                    h[j] += f.z * cw1s[(4 * k4 + 2) * HD + j];
                    h[j] += f.w * cw1s[(4 * k4 + 3) * HD + j];
                }
            }
            #pragma unroll
            for (int j = 0; j < HD; j++) sv += fmaxf(h[j], 0.f) * csw2[j];
        }
        float bs = block_reduce_256(sv);
        if (tid == 0) atomicAdd(&sums[4 + b], (double)bs);
    }
}

// ---------- pass 2: partition each level-1 bucket into SPP sub-ranges ----------
__global__ void __launch_bounds__(256) k_part2(
        const int* __restrict__ gcur, const unsigned* __restrict__ buf1,
        int* __restrict__ cur2, unsigned* __restrict__ buf2) {
    __shared__ int hist[SPP], gbase[SPP], lcur[SPP];
    int part = blockIdx.x / SLICES;
    int slice = blockIdx.x % SLICES;
    int count = min(gcur[part], PCAP);
    int base = slice * CHUNK2;
    if (base >= count) return;
    const unsigned* in = buf1 + (size_t)part * PCAP;
    int sub0 = part * SPP;
    int tid = threadIdx.x;
    if (tid < SPP) hist[tid] = 0;
    __syncthreads();
    unsigned ent[8]; int bin[8];
    #pragma unroll
    for (int k = 0; k < 8; k++) {
        int i = base + k * 256 + tid;
        if (i < count) {
            unsigned e = in[i];
            ent[k] = e;
            bin[k] = (int)((e >> 16) / (unsigned)SNODES) - sub0;
            atomicAdd(&hist[bin[k]], 1);
        } else bin[k] = -1;
    }
    __syncthreads();
    if (tid < SPP) { gbase[tid] = atomicAdd(&cur2[sub0 + tid], hist[tid]); lcur[tid] = 0; }
    __syncthreads();
    #pragma unroll
    for (int k = 0; k < 8; k++) {
        if (bin[k] >= 0) {
            int p = gbase[bin[k]] + atomicAdd(&lcur[bin[k]], 1);
            if (p < SCAP) buf2[(size_t)(sub0 + bin[k]) * SCAP + p] = ent[k];
        }
    }
}

// ---------- per-sub-range histogram -> cnt + dinv; also scales y1 -> z1 in place ----------
__global__ void __launch_bounds__(256) k_hist(
        const int* __restrict__ cur2, const unsigned* __restrict__ buf2,
        int* __restrict__ cnt, float* __restrict__ dinv, float* __restrict__ z1) {
    __shared__ int hist[SNODES];
    int tid = threadIdx.x, sub = blockIdx.x, vbase = sub * SNODES;
    if (tid < SNODES) hist[tid] = 0;
    __syncthreads();
    int count = min(cur2[sub], SCAP);
    const unsigned* in = buf2 + (size_t)sub * SCAP;
    for (int i = tid; i < count; i += 256)
        atomicAdd(&hist[(int)(in[i] >> 16) - vbase], 1);
    __syncthreads();
    if (tid < SNODES) {
        int c = hist[tid];
        cnt[vbase + tid] = c;
        dinv[vbase + tid] = rsqrtf((float)(4 * c + 1));
    }
    __syncthreads();
    if (tid < SNODES * 4) {
        int vl = tid >> 2, f4 = tid & 3;
        float dv = rsqrtf((float)(4 * hist[vl] + 1));
        float4* p = (float4*)&z1[(size_t)(vbase + vl) * HD + f4 * 4];
        float4 v = *p;
        *p = make_float4(dv * v.x, dv * v.y, dv * v.z, dv * v.w);
    }
}

// ---------- in-LDS counting sort using precomputed cnt + parallel scan ----------
__device__ inline void sort_sublist(int sub, const int* __restrict__ cur2,
                                    const int* __restrict__ cnt,
                                    const unsigned* __restrict__ buf2,
                                    unsigned* sorted, int* rp, int* cur, int* s) {
    int tid = threadIdx.x, vbase = sub * SNODES;
    int own = (tid < SNODES) ? cnt[vbase + tid] : 0;
    if (tid < 64) s[tid] = own;
    __syncthreads();
    #pragma unroll
    for (int off = 1; off < 64; off <<= 1) {
        int v = (tid < 64 && tid >= off) ? s[tid - off] : 0;
        __syncthreads();
        if (tid < 64) s[tid] += v;
        __syncthreads();
    }
    if (tid < SNODES) {
        int excl = s[tid] - own;
        rp[tid] = excl;
        cur[tid] = excl;
    }
    if (tid == SNODES - 1) rp[SNODES] = s[tid];
    __syncthreads();
    int count = min(cur2[sub], SCAP);
    const unsigned* in = buf2 + (size_t)sub * SCAP;
    for (int i = tid; i < count; i += 256) {
        unsigned e = in[i];
        int p = atomicAdd(&cur[(int)(e >> 16) - vbase], 1);
        sorted[p] = e;
    }
    __syncthreads();
}

__device__ inline void load_sorted(int sub, const int* __restrict__ cur2,
                                   const int* __restrict__ cnt,
                                   const unsigned* __restrict__ buf2,
                                   unsigned* sorted, int* rp, int* s) {
    int tid = threadIdx.x, vbase = sub * SNODES;
    int own = (tid < SNODES) ? cnt[vbase + tid] : 0;
    if (tid < 64) s[tid] = own;
    __syncthreads();
    #pragma unroll
    for (int off = 1; off < 64; off <<= 1) {
        int v = (tid < 64 && tid >= off) ? s[tid - off] : 0;
        __syncthreads();
        if (tid < 64) s[tid] += v;
        __syncthreads();
    }
    if (tid < SNODES) rp[tid] = s[tid] - own;
    if (tid == SNODES - 1) rp[SNODES] = s[tid];
    __syncthreads();
    int count = min(cur2[sub], SCAP);
    const unsigned* in = buf2 + (size_t)sub * SCAP;
    for (int i = tid; i < count; i += 256) sorted[i] = in[i];
    __syncthreads();
}

// ---------- per-node register gather over a sorted run (8 loads in flight) ----------
__device__ inline float gather_run(const unsigned* sorted, int s0, int s1,
                                   const float* __restrict__ z, int j) {
    float acc = 0.f;
    int i = s0;
    for (; i + 8 <= s1; i += 8) {
        unsigned e0 = sorted[i],   e1 = sorted[i+1], e2 = sorted[i+2], e3 = sorted[i+3];
        unsigned e4 = sorted[i+4], e5 = sorted[i+5], e6 = sorted[i+6], e7 = sorted[i+7];
        float v0 = z[(e0 & 0xffffu) * HD + j];
        float v1 = z[(e1 & 0xffffu) * HD + j];
        float v2 = z[(e2 & 0xffffu) * HD + j];
        float v3 = z[(e3 & 0xffffu) * HD + j];
        float v4 = z[(e4 & 0xffffu) * HD + j];
        float v5 = z[(e5 & 0xffffu) * HD + j];
        float v6 = z[(e6 & 0xffffu) * HD + j];
        float v7 = z[(e7 & 0xffffu) * HD + j];
        acc += ((v0 + v1) + (v2 + v3)) + ((v4 + v5) + (v6 + v7));
    }
    for (; i + 4 <= s1; i += 4) {
        unsigned a = sorted[i], b = sorted[i+1], c = sorted[i+2], d = sorted[i+3];
        float va = z[(a & 0xffffu) * HD + j];
        float vb = z[(b & 0xffffu) * HD + j];
        float vc = z[(c & 0xffffu) * HD + j];
        float vd = z[(d & 0xffffu) * HD + j];
        acc += (va + vb) + (vc + vd);
    }
    for (; i < s1; i++) acc += z[(sorted[i] & 0xffffu) * HD + j];
    return acc;
}

// ---------- conv1: sort + gather z1, finalize, z2 = dinv*(relu(.)@W2) ----------
__global__ void __launch_bounds__(256) k_conv1(
        const int* __restrict__ cur2, const int* __restrict__ cnt,
        unsigned* __restrict__ buf2,
        const float* __restrict__ dinv, const float* __restrict__ z1,
        const float* __restrict__ b1, const float* __restrict__ W2,
        float* __restrict__ z2) {
    __shared__ unsigned sorted[SCAP];
    __shared__ int rp[SNODES + 1], cur[SNODES], s[64];
    __shared__ float sW[HD * HD], sb[HD];
    int tid = threadIdx.x;
    if (tid < HD * HD) sW[tid] = W2[tid];
    if (tid < HD) sb[tid] = b1[tid];
    int sub = blockIdx.x, vbase = sub * SNODES;
    sort_sublist(sub, cur2, cnt, buf2, sorted, rp, cur, s);

    {   // write back sorted list for conv2 (block owns this region exclusively)
        int count = min(cur2[sub], SCAP);
        unsigned* outp = buf2 + (size_t)sub * SCAP;
        for (int i = tid; i < count; i += 256) outp[i] = sorted[i];
    }

    int j = tid & 15, g = tid >> 4;
    int sbase = (tid & 63) & 48;
    #pragma unroll
    for (int it = 0; it < (SNODES + 15) / 16; it++) {
        int lv = it * 16 + g;
        bool valid = (lv < SNODES);
        float h = 0.f, dv = 0.f;
        if (valid) {
            float acc = gather_run(sorted, rp[lv], rp[lv + 1], z1, j);
            int v = vbase + lv;
            dv = dinv[v];
            h = fmaxf(4.f * dv * acc + dv * z1[v * HD + j] + sb[j], 0.f);
        }
        float o = 0.f;
        #pragma unroll
        for (int k = 0; k < HD; k++) o += __shfl(h, sbase + k) * sW[k * HD + j];
        if (valid) z2[(vbase + lv) * HD + j] = dv * o;
    }
}

// ---------- conv2: load pre-sorted + gather z2, finalize, dot nfcW, reduce ----------
__global__ void __launch_bounds__(256) k_conv2(
        const int* __restrict__ cur2, const int* __restrict__ cnt,
        const unsigned* __restrict__ buf2,
        const float* __restrict__ dinv, const float* __restrict__ z2,
        const float* __restrict__ b2, const float* __restrict__ nfcW,
        double* __restrict__ sums) {
    __shared__ unsigned sorted[SCAP];
    __shared__ int rp[SNODES + 1], s[64];
    __shared__ float sb[HD], sw[HD];
    int tid = threadIdx.x;
    if (tid < HD) { sb[tid] = b2[tid]; sw[tid] = nfcW[tid]; }
    int sub = blockIdx.x, vbase = sub * SNODES;
    load_sorted(sub, cur2, cnt, buf2, sorted, rp, s);

    int j = tid & 15, g = tid >> 4;
    float part = 0.f;
    #pragma unroll
    for (int it = 0; it < (SNODES + 15) / 16; it++) {
        int lv = it * 16 + g;
        if (lv < SNODES) {
            float acc = gather_run(sorted, rp[lv], rp[lv + 1], z2, j);
            int v = vbase + lv;
            float dv = dinv[v];
            float h = fmaxf(4.f * dv * acc + dv * z2[v * HD + j] + sb[j], 0.f);
            part += h * sw[j];
        }
    }
    float bs = block_reduce_256(part);
    if (tid == 0) atomicAdd(&sums[0], (double)bs);
}

// ---------- final tiny head ----------
__global__ void k_final(const double* __restrict__ sums,
                        const float* __restrict__ nfcb, const float* __restrict__ cb2,
                        const float* __restrict__ fcW, const float* __restrict__ fcb,
                        const float* __restrict__ outW, const float* __restrict__ outb,
                        float* __restrict__ out) {
    int b = threadIdx.x;
    if (b < NBAT) {
        float na = (float)(sums[b] * (1.0 / NN)) + nfcb[0];
        float ca = (float)(sums[4 + b] * (1.0 / NC)) + cb2[0];
        float o = outb[0];
        #pragma unroll
        for (int j = 0; j < HD; j++) {
            float z = fmaxf(na * fcW[j] + ca * fcW[HD + j] + fcb[j], 0.f);
            o += z * outW[j];
        }
        out[b] = o;
    }
}

extern "C" void kernel_launch(void* const* d_in, const int* in_sizes, int n_in,
                              void* d_out, int out_size, void* d_ws, size_t ws_size,
                              hipStream_t stream) {
    const float* x    = (const float*)d_in[0];
    const float* col  = (const float*)d_in[1];
    const int*   ei   = (const int*)d_in[2];
    const float* W1   = (const float*)d_in[3];
    const float* b1   = (const float*)d_in[4];
    const float* W2   = (const float*)d_in[5];
    const float* b2   = (const float*)d_in[6];
    const float* nfcW = (const float*)d_in[7];
    const float* nfcb = (const float*)d_in[8];
    const float* cW1  = (const float*)d_in[9];
    const float* cb1  = (const float*)d_in[10];
    const float* cW2  = (const float*)d_in[11];
    const float* cb2  = (const float*)d_in[12];
    const float* fcW  = (const float*)d_in[13];
    const float* fcb  = (const float*)d_in[14];
    const float* outW = (const float*)d_in[15];
    const float* outb = (const float*)d_in[16];
    float* out = (float*)d_out;

    char* ws = (char*)d_ws;
    int*      gcur = (int*)     (ws + 0);          // 20 int
    int*      cur2 = (int*)     (ws + 128);        // 1000 int -> ends 4128
    double*   sums = (double*)  (ws + 4160);       // 8 doubles, own cache line -> ends 4224
    int*      cnt  = (int*)     (ws + 4224);       // 200000 B -> ends 204224
    float*    dinv = (float*)   (ws + 204224);     // 200000 B -> ends 404224
    unsigned* buf1 = (unsigned*)(ws + 404480);     // 7,040,000 B -> ends 7,444,480
    float*    z2   = (float*)   (ws + 404480);     // overlay on buf1 (dead after part2)
    float*    z1   = (float*)   (ws + 7444480);    // 3,200,000 B -> ends 10,644,480
    unsigned* buf2 = (unsigned*)(ws + 10644480);   // 8,192,000 B -> ends 18,836,480

    const int* src = ei;
    const int* dst = ei + NE;

    hipMemsetAsync(gcur, 0, 4224, stream);   // gcur + cur2 + sums in one dispatch

    k_mega <<<MEGAB, 256, 0, stream>>>(x, src, dst, col, W1, b1, W2, b2,
                                       nfcW, cW1, cb1, cW2, gcur, buf1, z1, sums);
    k_part2<<<NP * SLICES, 256, 0, stream>>>(gcur, buf1, cur2, buf2);
    k_hist <<<NSUB, 256, 0, stream>>>(cur2, buf2, cnt, dinv, z1);
    k_conv1<<<NSUB, 256, 0, stream>>>(cur2, cnt, buf2, dinv, z1, b1, W2, z2);
    k_conv2<<<NSUB, 256, 0, stream>>>(cur2, cnt, buf2, dinv, z2, b2, nfcW, sums);
    k_final<<<1, 64, 0, stream>>>(sums, nfcb, cb2, fcW, fcb, outW, outb, out);
}